// Round 1
// baseline (665.939 us; speedup 1.0000x reference)
//
#include <hip/hip_runtime.h>
#include <hip/hip_bf16.h>

// Problem constants (fixed by setup_inputs)
constexpr int TDIM = 16384;
constexpr int DIN  = 4096;
constexpr int DOUT = 4096;
constexpr int RNK  = 32;
constexpr float EPSF = 1e-8f;

using i32x4 = __attribute__((ext_vector_type(4))) int;

// ---------------------------------------------------------------------------
// Kernel 1: weight_eff = W + loraB @ loraA  -> per-row absmax -> int8 quantize
// 4 rows per block, 256 threads. Each thread owns 16 columns (4 x float4).
// ---------------------------------------------------------------------------
__global__ __launch_bounds__(256)
void wquant_kernel(const float* __restrict__ W,
                   const float* __restrict__ Amat,   // [32, 4096]
                   const float* __restrict__ Bmat,   // [4096, 32]
                   float* __restrict__ a_w,          // [4096]
                   signed char* __restrict__ qw)     // [4096, 4096]
{
    const int tid = threadIdx.x;
    const int o0  = blockIdx.x * 4;

    __shared__ float Bsh[4][32];
    __shared__ float red[4][4];   // [wave][row]
    __shared__ float awsh[4];

    if (tid < 128) {
        int r = tid >> 5, c = tid & 31;
        Bsh[r][c] = Bmat[(size_t)(o0 + r) * RNK + c];
    }
    __syncthreads();

    float4 acc[4][4];   // [row][col-chunk]
    #pragma unroll
    for (int c = 0; c < 4; ++c) {
        const int i4 = c * 1024 + tid * 4;
        #pragma unroll
        for (int r = 0; r < 4; ++r)
            acc[r][c] = *(const float4*)(W + (size_t)(o0 + r) * DIN + i4);
        for (int k = 0; k < RNK; ++k) {
            float4 a = *(const float4*)(Amat + (size_t)k * DIN + i4);
            #pragma unroll
            for (int r = 0; r < 4; ++r) {
                float b = Bsh[r][k];
                acc[r][c].x += b * a.x; acc[r][c].y += b * a.y;
                acc[r][c].z += b * a.z; acc[r][c].w += b * a.w;
            }
        }
    }

    // per-row absmax: wave shuffle reduce, then cross-wave via LDS
    const int wid = tid >> 6;
    #pragma unroll
    for (int r = 0; r < 4; ++r) {
        float m = 0.f;
        #pragma unroll
        for (int c = 0; c < 4; ++c) {
            float4 v = acc[r][c];
            m = fmaxf(m, fmaxf(fmaxf(fabsf(v.x), fabsf(v.y)),
                               fmaxf(fabsf(v.z), fabsf(v.w))));
        }
        for (int off = 1; off < 64; off <<= 1)
            m = fmaxf(m, __shfl_xor(m, off));
        if ((tid & 63) == 0) red[wid][r] = m;
    }
    __syncthreads();
    if (tid < 4) {
        float m = fmaxf(fmaxf(red[0][tid], red[1][tid]),
                        fmaxf(red[2][tid], red[3][tid]));
        float aw = m + EPSF;
        awsh[tid] = aw;
        a_w[o0 + tid] = aw;
    }
    __syncthreads();

    #pragma unroll
    for (int r = 0; r < 4; ++r) {
        const float aw = awsh[r];
        #pragma unroll
        for (int c = 0; c < 4; ++c) {
            float4 v = acc[r][c];
            // match reference: round((w/aw) * 127), round-half-even
            int q0 = __float2int_rn((v.x / aw) * 127.0f);
            int q1 = __float2int_rn((v.y / aw) * 127.0f);
            int q2 = __float2int_rn((v.z / aw) * 127.0f);
            int q3 = __float2int_rn((v.w / aw) * 127.0f);
            unsigned int packed = (q0 & 0xff) | ((q1 & 0xff) << 8) |
                                  ((q2 & 0xff) << 16) | ((q3 & 0xff) << 24);
            *(unsigned int*)(qw + (size_t)(o0 + r) * DIN + c * 1024 + tid * 4) = packed;
        }
    }
}

// ---------------------------------------------------------------------------
// Kernel 2: x quantize: qx = round(clip(x/a_x,-1,1)*127), int8
// Each thread: 16 floats -> 16 bytes (one uint4 store).
// ---------------------------------------------------------------------------
__global__ __launch_bounds__(256)
void xquant_kernel(const float* __restrict__ x,
                   const float* __restrict__ axp,
                   uint4* __restrict__ qx)
{
    const float inv = 1.0f / fmaxf(axp[0], EPSF);
    const size_t idx = (size_t)blockIdx.x * 256 + threadIdx.x;
    const float4* xv = (const float4*)x;

    unsigned int w[4];
    #pragma unroll
    for (int j = 0; j < 4; ++j) {
        float4 v = xv[idx * 4 + j];
        int q0 = __float2int_rn(fminf(fmaxf(v.x * inv, -1.f), 1.f) * 127.0f);
        int q1 = __float2int_rn(fminf(fmaxf(v.y * inv, -1.f), 1.f) * 127.0f);
        int q2 = __float2int_rn(fminf(fmaxf(v.z * inv, -1.f), 1.f) * 127.0f);
        int q3 = __float2int_rn(fminf(fmaxf(v.w * inv, -1.f), 1.f) * 127.0f);
        w[j] = (q0 & 0xff) | ((q1 & 0xff) << 8) | ((q2 & 0xff) << 16) | ((q3 & 0xff) << 24);
    }
    qx[idx] = make_uint4(w[0], w[1], w[2], w[3]);
}

// ---------------------------------------------------------------------------
// Kernel 3: int8 GEMM  out[t,o] = acc(qx[t,:]·qw[o,:]) * (ax*a_w[o]/127^2) + bias[o]
// m97 structure: 128x128 tile, BK=64 bytes, 4 waves (2x2), 4x4 16x16x64 frags,
// global_load_lds width 16, single LDS buffer, 2 barriers per K-step.
// LDS layout: [128][64] i8 with 16B-block XOR swizzle kb ^= (row^(row>>2))&3,
// applied by pre-swizzling the GLOBAL source (linear LDS dest) per rule #21.
// ---------------------------------------------------------------------------
__global__ __launch_bounds__(256, 2)
void gemm_i8_kernel(const signed char* __restrict__ qx,   // [16384, 4096]
                    const signed char* __restrict__ qw,   // [4096, 4096]
                    const float* __restrict__ a_w,        // [4096]
                    const float* __restrict__ bias,       // [4096]
                    const float* __restrict__ axp,
                    float* __restrict__ out)              // [16384, 4096]
{
    __shared__ signed char As[128 * 64];   // 8 KB
    __shared__ signed char Bs[128 * 64];   // 8 KB

    const int tid  = threadIdx.x;
    const int lane = tid & 63;
    const int wid  = tid >> 6;
    const int wm   = wid >> 1;    // 0..1
    const int wn   = wid & 1;     // 0..1

    // n fastest so 32 consecutive blocks share the same qx M-panel
    const int bid = blockIdx.x;
    const int nb  = bid & 31;
    const int mb  = bid >> 5;

    const size_t K = DIN;

    // ---- staging addressing (per thread: 16B; 2 insts each for A and B) ----
    const int srow = tid >> 2;                 // 0..63 (j adds 64)
    const int skb  = tid & 3;                  // 16B block within 64B row
    const int ssw  = (srow ^ (srow >> 2)) & 3; // swizzle key (row low bits only)
    const int skb2 = skb ^ ssw;                // pre-swizzled global block

    const signed char* aSrc = qx + (size_t)(mb * 128) * K;
    const signed char* bSrc = qw + (size_t)(nb * 128) * K;

    // ---- fragment read addressing ----
    const int r15 = lane & 15;
    const int rsw = (r15 ^ (r15 >> 2)) & 3;
    const int rkb = (((lane >> 4) ^ rsw) << 4);          // swizzled 16B block
    const int aRdBase = (wm * 64 + r15) * 64 + rkb;      // + m*1024
    const int bRdBase = (wn * 64 + r15) * 64 + rkb;      // + n*1024

    i32x4 zero = {0, 0, 0, 0};
    i32x4 acc[4][4];
    #pragma unroll
    for (int m = 0; m < 4; ++m)
        #pragma unroll
        for (int n = 0; n < 4; ++n) acc[m][n] = zero;

    for (int kt = 0; kt < (int)(K / 64); ++kt) {
        const size_t kOff = (size_t)kt * 64;
        #pragma unroll
        for (int j = 0; j < 2; ++j) {
            const int row = j * 64 + srow;
            __builtin_amdgcn_global_load_lds(
                (const __attribute__((address_space(1))) unsigned int*)
                    (aSrc + (size_t)row * K + kOff + skb2 * 16),
                (__attribute__((address_space(3))) unsigned int*)
                    (As + j * 4096 + tid * 16),
                16, 0, 0);
        }
        #pragma unroll
        for (int j = 0; j < 2; ++j) {
            const int row = j * 64 + srow;
            __builtin_amdgcn_global_load_lds(
                (const __attribute__((address_space(1))) unsigned int*)
                    (bSrc + (size_t)row * K + kOff + skb2 * 16),
                (__attribute__((address_space(3))) unsigned int*)
                    (Bs + j * 4096 + tid * 16),
                16, 0, 0);
        }
        __syncthreads();   // compiler drains vmcnt before s_barrier

        i32x4 af[4], bf[4];
        #pragma unroll
        for (int m = 0; m < 4; ++m)
            af[m] = *(const i32x4*)(As + aRdBase + m * 1024);
        #pragma unroll
        for (int n = 0; n < 4; ++n)
            bf[n] = *(const i32x4*)(Bs + bRdBase + n * 1024);

        #pragma unroll
        for (int m = 0; m < 4; ++m)
            #pragma unroll
            for (int n = 0; n < 4; ++n)
                acc[m][n] = __builtin_amdgcn_mfma_i32_16x16x64_i8(
                    af[m], bf[n], acc[m][n], 0, 0, 0);

        __syncthreads();   // protect single LDS buffer before next stage
    }

    // ---- epilogue: C/D layout col=lane&15, row=(lane>>4)*4+reg ----
    const float ax = fmaxf(axp[0], EPSF);
    #pragma unroll
    for (int n = 0; n < 4; ++n) {
        const int o = nb * 128 + wn * 64 + n * 16 + r15;
        const float scale = ax * a_w[o] * (1.0f / 16129.0f);
        const float bs = bias[o];
        #pragma unroll
        for (int m = 0; m < 4; ++m) {
            const int t0 = mb * 128 + wm * 64 + m * 16 + ((lane >> 4) << 2);
            float* op = out + (size_t)t0 * DOUT + o;
            #pragma unroll
            for (int r = 0; r < 4; ++r)
                op[(size_t)r * DOUT] = (float)acc[m][n][r] * scale + bs;
        }
    }
}

// ---------------------------------------------------------------------------
extern "C" void kernel_launch(void* const* d_in, const int* in_sizes, int n_in,
                              void* d_out, int out_size, void* d_ws, size_t ws_size,
                              hipStream_t stream)
{
    const float* x    = (const float*)d_in[0];
    const float* W    = (const float*)d_in[1];
    const float* lA   = (const float*)d_in[2];
    const float* lB   = (const float*)d_in[3];
    const float* bias = (const float*)d_in[4];
    const float* ax   = (const float*)d_in[5];
    float* out        = (float*)d_out;

    // workspace: qx (64MB) | qw (16MB) | a_w (16KB)
    signed char* qx = (signed char*)d_ws;
    signed char* qw = qx + (size_t)TDIM * DIN;
    float* a_w      = (float*)(qw + (size_t)DOUT * DIN);

    wquant_kernel<<<DOUT / 4, 256, 0, stream>>>(W, lA, lB, a_w, qw);

    const int xblocks = (int)(((size_t)TDIM * DIN) / (16 * 256));  // 16384
    xquant_kernel<<<xblocks, 256, 0, stream>>>(x, ax, (uint4*)qx);

    gemm_i8_kernel<<<(TDIM / 128) * (DOUT / 128), 256, 0, stream>>>(
        qx, qw, a_w, bias, ax, out);
}

// Round 2
// 457.043 us; speedup vs baseline: 1.4571x; 1.4571x over previous
//
#include <hip/hip_runtime.h>
#include <hip/hip_bf16.h>

// Problem constants (fixed by setup_inputs)
constexpr int TDIM = 16384;
constexpr int DIN  = 4096;
constexpr int DOUT = 4096;
constexpr int RNK  = 32;
constexpr float EPSF = 1e-8f;

using i32x4 = __attribute__((ext_vector_type(4))) int;

// ---------------------------------------------------------------------------
// Kernel 1: weight_eff = W + loraB @ loraA  -> per-row absmax -> int8 quantize
// 4 rows per block, 256 threads, each thread owns 16 columns (4 x float4).
// k-outer loop: 4 independent A float4 loads per k for ILP.
// ---------------------------------------------------------------------------
__global__ __launch_bounds__(256)
void wquant_kernel(const float* __restrict__ W,
                   const float* __restrict__ Amat,   // [32, 4096]
                   const float* __restrict__ Bmat,   // [4096, 32]
                   float* __restrict__ a_w,          // [4096]
                   signed char* __restrict__ qw)     // [4096, 4096]
{
    const int tid = threadIdx.x;
    const int o0  = blockIdx.x * 4;

    __shared__ float Bsh[4][32];
    __shared__ float red[4][4];   // [wave][row]
    __shared__ float awsh[4];

    if (tid < 128) {
        int r = tid >> 5, c = tid & 31;
        Bsh[r][c] = Bmat[(size_t)(o0 + r) * RNK + c];
    }
    __syncthreads();

    float4 acc[4][4];   // [row][col-chunk]
    #pragma unroll
    for (int r = 0; r < 4; ++r)
        #pragma unroll
        for (int c = 0; c < 4; ++c)
            acc[r][c] = *(const float4*)(W + (size_t)(o0 + r) * DIN + c * 1024 + tid * 4);

    #pragma unroll 4
    for (int k = 0; k < RNK; ++k) {
        float4 a[4];
        #pragma unroll
        for (int c = 0; c < 4; ++c)
            a[c] = *(const float4*)(Amat + (size_t)k * DIN + c * 1024 + tid * 4);
        #pragma unroll
        for (int r = 0; r < 4; ++r) {
            const float b = Bsh[r][k];
            #pragma unroll
            for (int c = 0; c < 4; ++c) {
                acc[r][c].x += b * a[c].x; acc[r][c].y += b * a[c].y;
                acc[r][c].z += b * a[c].z; acc[r][c].w += b * a[c].w;
            }
        }
    }

    // per-row absmax: wave shuffle reduce, then cross-wave via LDS
    const int wid = tid >> 6;
    #pragma unroll
    for (int r = 0; r < 4; ++r) {
        float m = 0.f;
        #pragma unroll
        for (int c = 0; c < 4; ++c) {
            float4 v = acc[r][c];
            m = fmaxf(m, fmaxf(fmaxf(fabsf(v.x), fabsf(v.y)),
                               fmaxf(fabsf(v.z), fabsf(v.w))));
        }
        for (int off = 1; off < 64; off <<= 1)
            m = fmaxf(m, __shfl_xor(m, off));
        if ((tid & 63) == 0) red[wid][r] = m;
    }
    __syncthreads();
    if (tid < 4) {
        float m = fmaxf(fmaxf(red[0][tid], red[1][tid]),
                        fmaxf(red[2][tid], red[3][tid]));
        float aw = m + EPSF;
        awsh[tid] = aw;
        a_w[o0 + tid] = aw;
    }
    __syncthreads();

    #pragma unroll
    for (int r = 0; r < 4; ++r) {
        const float aw = awsh[r];
        #pragma unroll
        for (int c = 0; c < 4; ++c) {
            float4 v = acc[r][c];
            int q0 = __float2int_rn((v.x / aw) * 127.0f);
            int q1 = __float2int_rn((v.y / aw) * 127.0f);
            int q2 = __float2int_rn((v.z / aw) * 127.0f);
            int q3 = __float2int_rn((v.w / aw) * 127.0f);
            unsigned int packed = (q0 & 0xff) | ((q1 & 0xff) << 8) |
                                  ((q2 & 0xff) << 16) | ((q3 & 0xff) << 24);
            *(unsigned int*)(qw + (size_t)(o0 + r) * DIN + c * 1024 + tid * 4) = packed;
        }
    }
}

// ---------------------------------------------------------------------------
// Kernel 2: x quantize: qx = round(clip(x/a_x,-1,1)*127), int8
// COALESCED: lane-consecutive float4 loads (16B/lane), lane-consecutive
// 4B packed stores. Each thread handles 4 float4s at j*256 stride.
// ---------------------------------------------------------------------------
__global__ __launch_bounds__(256)
void xquant_kernel(const float* __restrict__ x,
                   const float* __restrict__ axp,
                   unsigned int* __restrict__ qx)   // one uint per float4
{
    const float inv = 1.0f / fmaxf(axp[0], EPSF);
    const size_t base = (size_t)blockIdx.x * 1024 + threadIdx.x;
    const float4* xv = (const float4*)x;

    float4 v[4];
    #pragma unroll
    for (int j = 0; j < 4; ++j)
        v[j] = xv[base + j * 256];

    #pragma unroll
    for (int j = 0; j < 4; ++j) {
        int q0 = __float2int_rn(fminf(fmaxf(v[j].x * inv, -1.f), 1.f) * 127.0f);
        int q1 = __float2int_rn(fminf(fmaxf(v[j].y * inv, -1.f), 1.f) * 127.0f);
        int q2 = __float2int_rn(fminf(fmaxf(v[j].z * inv, -1.f), 1.f) * 127.0f);
        int q3 = __float2int_rn(fminf(fmaxf(v[j].w * inv, -1.f), 1.f) * 127.0f);
        qx[base + j * 256] = (q0 & 0xff) | ((q1 & 0xff) << 8) |
                             ((q2 & 0xff) << 16) | ((q3 & 0xff) << 24);
    }
}

// ---------------------------------------------------------------------------
// Kernel 3: int8 GEMM (UNCHANGED from round 1 — passed, 350us, MfmaUtil 35.5%)
// m97 structure: 128x128 tile, BK=64 bytes, 4 waves (2x2), 4x4 16x16x64 frags,
// global_load_lds width 16, single LDS buffer, 2 barriers per K-step.
// ---------------------------------------------------------------------------
__global__ __launch_bounds__(256, 2)
void gemm_i8_kernel(const signed char* __restrict__ qx,   // [16384, 4096]
                    const signed char* __restrict__ qw,   // [4096, 4096]
                    const float* __restrict__ a_w,        // [4096]
                    const float* __restrict__ bias,       // [4096]
                    const float* __restrict__ axp,
                    float* __restrict__ out)              // [16384, 4096]
{
    __shared__ signed char As[128 * 64];   // 8 KB
    __shared__ signed char Bs[128 * 64];   // 8 KB

    const int tid  = threadIdx.x;
    const int lane = tid & 63;
    const int wid  = tid >> 6;
    const int wm   = wid >> 1;    // 0..1
    const int wn   = wid & 1;     // 0..1

    const int bid = blockIdx.x;
    const int nb  = bid & 31;
    const int mb  = bid >> 5;

    const size_t K = DIN;

    const int srow = tid >> 2;                 // 0..63 (j adds 64)
    const int skb  = tid & 3;                  // 16B block within 64B row
    const int ssw  = (srow ^ (srow >> 2)) & 3; // swizzle key
    const int skb2 = skb ^ ssw;                // pre-swizzled global block

    const signed char* aSrc = qx + (size_t)(mb * 128) * K;
    const signed char* bSrc = qw + (size_t)(nb * 128) * K;

    const int r15 = lane & 15;
    const int rsw = (r15 ^ (r15 >> 2)) & 3;
    const int rkb = (((lane >> 4) ^ rsw) << 4);          // swizzled 16B block
    const int aRdBase = (wm * 64 + r15) * 64 + rkb;      // + m*1024
    const int bRdBase = (wn * 64 + r15) * 64 + rkb;      // + n*1024

    i32x4 zero = {0, 0, 0, 0};
    i32x4 acc[4][4];
    #pragma unroll
    for (int m = 0; m < 4; ++m)
        #pragma unroll
        for (int n = 0; n < 4; ++n) acc[m][n] = zero;

    for (int kt = 0; kt < (int)(K / 64); ++kt) {
        const size_t kOff = (size_t)kt * 64;
        #pragma unroll
        for (int j = 0; j < 2; ++j) {
            const int row = j * 64 + srow;
            __builtin_amdgcn_global_load_lds(
                (const __attribute__((address_space(1))) unsigned int*)
                    (aSrc + (size_t)row * K + kOff + skb2 * 16),
                (__attribute__((address_space(3))) unsigned int*)
                    (As + j * 4096 + tid * 16),
                16, 0, 0);
        }
        #pragma unroll
        for (int j = 0; j < 2; ++j) {
            const int row = j * 64 + srow;
            __builtin_amdgcn_global_load_lds(
                (const __attribute__((address_space(1))) unsigned int*)
                    (bSrc + (size_t)row * K + kOff + skb2 * 16),
                (__attribute__((address_space(3))) unsigned int*)
                    (Bs + j * 4096 + tid * 16),
                16, 0, 0);
        }
        __syncthreads();

        i32x4 af[4], bf[4];
        #pragma unroll
        for (int m = 0; m < 4; ++m)
            af[m] = *(const i32x4*)(As + aRdBase + m * 1024);
        #pragma unroll
        for (int n = 0; n < 4; ++n)
            bf[n] = *(const i32x4*)(Bs + bRdBase + n * 1024);

        #pragma unroll
        for (int m = 0; m < 4; ++m)
            #pragma unroll
            for (int n = 0; n < 4; ++n)
                acc[m][n] = __builtin_amdgcn_mfma_i32_16x16x64_i8(
                    af[m], bf[n], acc[m][n], 0, 0, 0);

        __syncthreads();
    }

    // ---- epilogue: C/D layout col=lane&15, row=(lane>>4)*4+reg ----
    const float ax = fmaxf(axp[0], EPSF);
    #pragma unroll
    for (int n = 0; n < 4; ++n) {
        const int o = nb * 128 + wn * 64 + n * 16 + r15;
        const float scale = ax * a_w[o] * (1.0f / 16129.0f);
        const float bs = bias[o];
        #pragma unroll
        for (int m = 0; m < 4; ++m) {
            const int t0 = mb * 128 + wm * 64 + m * 16 + ((lane >> 4) << 2);
            float* op = out + (size_t)t0 * DOUT + o;
            #pragma unroll
            for (int r = 0; r < 4; ++r)
                op[(size_t)r * DOUT] = (float)acc[m][n][r] * scale + bs;
        }
    }
}

// ---------------------------------------------------------------------------
extern "C" void kernel_launch(void* const* d_in, const int* in_sizes, int n_in,
                              void* d_out, int out_size, void* d_ws, size_t ws_size,
                              hipStream_t stream)
{
    const float* x    = (const float*)d_in[0];
    const float* W    = (const float*)d_in[1];
    const float* lA   = (const float*)d_in[2];
    const float* lB   = (const float*)d_in[3];
    const float* bias = (const float*)d_in[4];
    const float* ax   = (const float*)d_in[5];
    float* out        = (float*)d_out;

    // workspace: qx (64MB) | qw (16MB) | a_w (16KB)
    signed char* qx = (signed char*)d_ws;
    signed char* qw = qx + (size_t)TDIM * DIN;
    float* a_w      = (float*)(qw + (size_t)DOUT * DIN);

    wquant_kernel<<<DOUT / 4, 256, 0, stream>>>(W, lA, lB, a_w, qw);

    const int xblocks = (int)(((size_t)TDIM * DIN) / (16 * 256));  // 16384
    xquant_kernel<<<xblocks, 256, 0, stream>>>(x, ax, (unsigned int*)qx);

    gemm_i8_kernel<<<(TDIM / 128) * (DOUT / 128), 256, 0, stream>>>(
        qx, qw, a_w, bias, ax, out);
}